// Round 16
// baseline (229.306 us; speedup 1.0000x reference)
//
#include <hip/hip_runtime.h>

#if defined(__has_builtin)
#if __has_builtin(__builtin_amdgcn_readlane)
#define READLANE(v, l) __builtin_amdgcn_readlane((v), (l))
#else
#define READLANE(v, l) __shfl((v), (l))
#endif
#else
#define READLANE(v, l) __shfl((v), (l))
#endif
// float-safe lane read (R7/R8 lesson: raw readlane on float value-converts to 0)
__device__ __forceinline__ float readlane_f(float v, int l) {
    return __uint_as_float(READLANE(__float_as_uint(v), l));
}

// bf16 helpers. Randomly-gathered tables must fit per-XCD 4MB L2 (R13/R14).
__device__ __forceinline__ unsigned short f2bf(float x) {
    unsigned u = __float_as_uint(x);
    u += 0x7FFFu + ((u >> 16) & 1u);
    return (unsigned short)(u >> 16);
}

#define CAPLOG 8   // bucketed CSR: 256 slots/node (mean deg 32; tail ~0)

// ---------------------------------------------------------------------------
// prep0: convert src_emb fp32->bf16, zero cursor, zero bf16 sentinel rows.
// ---------------------------------------------------------------------------
__global__ __launch_bounds__(256) void prep0_k(
    const float* __restrict__ src_emb, unsigned short* __restrict__ sbf, int ve,
    int* __restrict__ cursor, int n,
    unsigned* __restrict__ Cz, unsigned* __restrict__ Az, int convB)
{
    const int b = blockIdx.x, t = threadIdx.x;
    if (b < convB) {
        int i = (b * 256 + t) * 4;
        if (i + 3 < ve) {
            float4 v = *(const float4*)&src_emb[i];
            ushort4 u;
            u.x = f2bf(v.x); u.y = f2bf(v.y); u.z = f2bf(v.z); u.w = f2bf(v.w);
            *(ushort4*)&sbf[i] = u;
        } else {
            for (; i < ve; ++i) sbf[i] = f2bf(src_emb[i]);
        }
    } else {
        int i = (b - convB) * 256 + t;
        if (i < n) cursor[i] = 0;
        if (b == convB && t < 32) { Cz[t] = 0u; Az[t] = 0u; }
    }
}

// ---------------------------------------------------------------------------
// prep1: co-launched CSR fill (first eB blocks) + embedding.
// Embed R16: one dword load covers TWO bf16 rows (lanes 0-31 row A pairs,
// 32-63 row B) -> 8 loads per wave-batch (was 16); LDS tile stored as raw
// bf16-pair dwords (64x33, stride 33 -> conflict-free) -> 8.4 KB, ~12 KB
// total -> 8 blocks/CU (was 5). R15 showed gather is L2-hit-latency bound:
// this doubles load width AND raises waves-in-flight.
// ---------------------------------------------------------------------------
__global__ __launch_bounds__(256) void prep1_k(
    const int* __restrict__ si, const int* __restrict__ di,
    int* __restrict__ cursor, int* __restrict__ edge_off, int ne, int eB,
    const int* __restrict__ src, const int* __restrict__ seg,
    const unsigned short* __restrict__ sbf, const float* __restrict__ seg_emb,
    const float* __restrict__ wvec, float* __restrict__ f)
{
    const int t = threadIdx.x;
    if ((int)blockIdx.x < eB) {                       // ---- CSR fill ----
        int i = blockIdx.x * 256 + t;
        if (i < ne) {
            int d = di[i];
            int pos = atomicAdd(cursor + d, 1);
            edge_off[((long)d << CAPLOG) + pos] = si[i] << 7;  // bf16 row stride
        }
        return;
    }
    // ---- embedding ----
    __shared__ unsigned Sb[64 * 33];      // bf16-pair tile (8.25 KB)
    __shared__ float red[4][64];
    __shared__ float part2[4][64];
    __shared__ float coefS[64];
    __shared__ float rGs[64];
    __shared__ float segE[192];
    __shared__ float dG[3];
    __shared__ int   gidxS[64];
    __shared__ int   cnt3[3];

    const int wid = t >> 6, q = t & 63;
    const long n = blockIdx.x - eB;

    if (wid == 0) {
        int c = seg[n * 64 + q];
        gidxS[q] = c;
        unsigned long long b0 = __ballot(c == 0);
        unsigned long long b1 = __ballot(c == 1);
        if (q == 0) {
            int n0 = __popcll(b0), n1 = __popcll(b1);
            cnt3[0] = n0; cnt3[1] = n1; cnt3[2] = 64 - n0 - n1;
        }
    } else if (t < 64 + 192) {
        segE[t - 64] = seg_emb[t - 64];
    }

    const int p0 = wid * 16;
    int off = src[n * 64 + p0 + (q & 15)] << 7;   // bf16 row byte offset
    const char* base = (const char*)sbf;
    const int h = q >> 5, c = q & 31;             // half-wave, column-pair idx
    const int cb = c << 2;                        // byte offset of col pair
    float s2lo = 0.f, s2hi = 0.f;
    #pragma unroll
    for (int pp = 0; pp < 8; ++pp) {
        int so = __shfl(off, 2 * pp + h);         // row p0+2pp+h byte offset
        unsigned d = *(const unsigned*)(base + (so + cb));
        Sb[(p0 + 2 * pp + h) * 33 + c] = d;
        float lo = __uint_as_float(d << 16);      // col 2c
        float hi = __uint_as_float(d & 0xFFFF0000u);  // col 2c+1
        s2lo += lo * lo;
        s2hi += hi * hi;
    }
    // combine the two half-wave row groups -> per-column sums over 16 rows
    s2lo += __shfl_xor(s2lo, 32);
    s2hi += __shfl_xor(s2hi, 32);
    if (h == 0) { red[wid][2 * c] = s2lo; red[wid][2 * c + 1] = s2hi; }
    __syncthreads();

    if (t < 64) {
        float ts = red[0][t] + red[1][t] + red[2][t] + red[3][t];
        float wq = wvec[t];
        coefS[t] = wq / fmaxf(fabsf(wq) * sqrtf(ts), 1e-12f);
        float e0 = segE[t], e1 = segE[64 + t], e2 = segE[128 + t];
        float g2 = (float)cnt3[0] * e0 * e0 + (float)cnt3[1] * e1 * e1
                 + (float)cnt3[2] * e2 * e2;
        rGs[t] = 1.f / fmaxf(sqrtf(g2), 1e-12f);
    }
    __syncthreads();

    if (t < 3) {
        float a = 0.f;
        for (int k = 0; k < 64; ++k) a += segE[t * 64 + k] * rGs[k];
        dG[t] = a;
    }
    // stage 2: lane q = token row; wave wid covers dword-columns wid*8..+7
    float acc = 0.f;
    const int c0 = wid * 8;
    #pragma unroll
    for (int cc = 0; cc < 8; ++cc) {
        unsigned d = Sb[q * 33 + c0 + cc];
        float lo = __uint_as_float(d << 16);
        float hi = __uint_as_float(d & 0xFFFF0000u);
        acc += lo * coefS[(c0 + cc) * 2] + hi * coefS[(c0 + cc) * 2 + 1];
    }
    part2[wid][q] = acc;
    __syncthreads();

    if (t < 64)
        f[n * 64 + t] = part2[0][t] + part2[1][t] + part2[2][t] + part2[3][t]
                        + dG[gidxS[t]];
}

// ---------------------------------------------------------------------------
// bf16 CSR gather, 4 rows per dwordx2 load (R14)
// ---------------------------------------------------------------------------
__device__ __forceinline__ float4 csr_gather4_bf(const char* __restrict__ hb,
                                                 const int* __restrict__ eo,
                                                 int dn, int j, int zoff)
{
    const int grp = j >> 4;
    const int col = (j & 15) << 3;
    float4 a0 = make_float4(0.f, 0.f, 0.f, 0.f);
    float4 a1 = a0, a2 = a0, a3 = a0;
#define ACC(d, a)                                                        \
    { a.x += __uint_as_float((d).x << 16);                               \
      a.y += __uint_as_float((d).x & 0xFFFF0000u);                       \
      a.z += __uint_as_float((d).y << 16);                               \
      a.w += __uint_as_float((d).y & 0xFFFF0000u); }
    for (int e = 0; e < dn; e += 64) {
        const int cnt = min(dn - e, 64);
        const int eoff = (e + j < dn) ? eo[e + j] : zoff;
        int m = 0;
        for (; m + 16 <= cnt; m += 16) {
            int o0 = __shfl(eoff, m + grp);
            int o1 = __shfl(eoff, m + 4 + grp);
            int o2 = __shfl(eoff, m + 8 + grp);
            int o3 = __shfl(eoff, m + 12 + grp);
            uint2 d0 = *(const uint2*)(hb + (o0 + col));
            uint2 d1 = *(const uint2*)(hb + (o1 + col));
            uint2 d2 = *(const uint2*)(hb + (o2 + col));
            uint2 d3 = *(const uint2*)(hb + (o3 + col));
            ACC(d0, a0); ACC(d1, a1); ACC(d2, a2); ACC(d3, a3);
        }
        for (; m < cnt; m += 4) {
            int o = __shfl(eoff, m + grp);
            uint2 d = *(const uint2*)(hb + (o + col));
            ACC(d, a0);
        }
    }
#undef ACC
    a0.x += a1.x + a2.x + a3.x;
    a0.y += a1.y + a2.y + a3.y;
    a0.z += a1.z + a2.z + a3.z;
    a0.w += a1.w + a2.w + a3.w;
    a0.x += __shfl_xor(a0.x, 16); a0.x += __shfl_xor(a0.x, 32);
    a0.y += __shfl_xor(a0.y, 16); a0.y += __shfl_xor(a0.y, 32);
    a0.z += __shfl_xor(a0.z, 16); a0.z += __shfl_xor(a0.z, 32);
    a0.w += __shfl_xor(a0.w, 16); a0.w += __shfl_xor(a0.w, 32);
    return a0;
}

__device__ __forceinline__ float4 bf_row4(const char* hb, long rowoff, int col) {
    uint2 d = *(const uint2*)(hb + rowoff + col);
    float4 v;
    v.x = __uint_as_float(d.x << 16);
    v.y = __uint_as_float(d.x & 0xFFFF0000u);
    v.z = __uint_as_float(d.y << 16);
    v.w = __uint_as_float(d.y & 0xFFFF0000u);
    return v;
}

// ---------------------------------------------------------------------------
// dense-pair core, split-K (16 KB weight half-tile, 28 KB LDS -> 5 blocks/CU):
//   H = relu(F@W1 + b1); out_bf16[r] = rsqrt(deg[r]+1) * (H@W2 (+ b2))
// ---------------------------------------------------------------------------
template <bool S2_BIAS>
__device__ __forceinline__ void dense_pair_body(
    float* Wh, float* F, float* H,
    const float* __restrict__ W1, const float* __restrict__ b1,
    const float* __restrict__ W2, const float* __restrict__ b2,
    const int* __restrict__ deg, unsigned short* __restrict__ out,
    int row0, int nrows, int t)
{
    for (int i = t * 4; i < 32 * 128; i += 1024)
        *(float4*)&Wh[i] = *(const float4*)&W1[i];
    __syncthreads();

    const int jg = t & 31, rslot = t >> 5;
    const int j0 = jg * 4;
    float4 acc0, acc1;
    {
        float4 b4 = *(const float4*)&b1[j0];
        acc0 = b4; acc1 = b4;
    }
    #pragma unroll 2
    for (int k = 0; k < 32; k += 4) {
        float4 w0 = *(float4*)&Wh[(k + 0) * 128 + j0];
        float4 w1 = *(float4*)&Wh[(k + 1) * 128 + j0];
        float4 w2 = *(float4*)&Wh[(k + 2) * 128 + j0];
        float4 w3 = *(float4*)&Wh[(k + 3) * 128 + j0];
        float4 fa = *(float4*)&F[rslot * 64 + k];
        float4 fb = *(float4*)&F[(rslot + 8) * 64 + k];
        acc0.x += fa.x * w0.x + fa.y * w1.x + fa.z * w2.x + fa.w * w3.x;
        acc0.y += fa.x * w0.y + fa.y * w1.y + fa.z * w2.y + fa.w * w3.y;
        acc0.z += fa.x * w0.z + fa.y * w1.z + fa.z * w2.z + fa.w * w3.z;
        acc0.w += fa.x * w0.w + fa.y * w1.w + fa.z * w2.w + fa.w * w3.w;
        acc1.x += fb.x * w0.x + fb.y * w1.x + fb.z * w2.x + fb.w * w3.x;
        acc1.y += fb.x * w0.y + fb.y * w1.y + fb.z * w2.y + fb.w * w3.y;
        acc1.z += fb.x * w0.z + fb.y * w1.z + fb.z * w2.z + fb.w * w3.z;
        acc1.w += fb.x * w0.w + fb.y * w1.w + fb.z * w2.w + fb.w * w3.w;
    }
    __syncthreads();
    for (int i = t * 4; i < 32 * 128; i += 1024)
        *(float4*)&Wh[i] = *(const float4*)&W1[32 * 128 + i];
    __syncthreads();
    #pragma unroll 2
    for (int k = 0; k < 32; k += 4) {
        float4 w0 = *(float4*)&Wh[(k + 0) * 128 + j0];
        float4 w1 = *(float4*)&Wh[(k + 1) * 128 + j0];
        float4 w2 = *(float4*)&Wh[(k + 2) * 128 + j0];
        float4 w3 = *(float4*)&Wh[(k + 3) * 128 + j0];
        float4 fa = *(float4*)&F[rslot * 64 + 32 + k];
        float4 fb = *(float4*)&F[(rslot + 8) * 64 + 32 + k];
        acc0.x += fa.x * w0.x + fa.y * w1.x + fa.z * w2.x + fa.w * w3.x;
        acc0.y += fa.x * w0.y + fa.y * w1.y + fa.z * w2.y + fa.w * w3.y;
        acc0.z += fa.x * w0.z + fa.y * w1.z + fa.z * w2.z + fa.w * w3.z;
        acc0.w += fa.x * w0.w + fa.y * w1.w + fa.z * w2.w + fa.w * w3.w;
        acc1.x += fb.x * w0.x + fb.y * w1.x + fb.z * w2.x + fb.w * w3.x;
        acc1.y += fb.x * w0.y + fb.y * w1.y + fb.z * w2.y + fb.w * w3.y;
        acc1.z += fb.x * w0.z + fb.y * w1.z + fb.z * w2.z + fb.w * w3.z;
        acc1.w += fb.x * w0.w + fb.y * w1.w + fb.z * w2.w + fb.w * w3.w;
    }
    {
        float4 v;
        v.x = fmaxf(acc0.x, 0.f); v.y = fmaxf(acc0.y, 0.f);
        v.z = fmaxf(acc0.z, 0.f); v.w = fmaxf(acc0.w, 0.f);
        *(float4*)&H[rslot * 128 + j0] = v;
        v.x = fmaxf(acc1.x, 0.f); v.y = fmaxf(acc1.y, 0.f);
        v.z = fmaxf(acc1.z, 0.f); v.w = fmaxf(acc1.w, 0.f);
        *(float4*)&H[(rslot + 8) * 128 + j0] = v;
    }
    __syncthreads();

    for (int i = t * 4; i < 64 * 64; i += 1024)
        *(float4*)&Wh[i] = *(const float4*)&W2[i];
    __syncthreads();
    const int jg2 = t & 15, r2 = t >> 4;
    const int j02 = jg2 * 4;
    float4 acc = S2_BIAS ? *(const float4*)&b2[j02]
                         : make_float4(0.f, 0.f, 0.f, 0.f);
    #pragma unroll 2
    for (int k = 0; k < 64; k += 4) {
        float4 w0 = *(float4*)&Wh[(k + 0) * 64 + j02];
        float4 w1 = *(float4*)&Wh[(k + 1) * 64 + j02];
        float4 w2 = *(float4*)&Wh[(k + 2) * 64 + j02];
        float4 w3 = *(float4*)&Wh[(k + 3) * 64 + j02];
        float4 fq = *(float4*)&H[r2 * 128 + k];
        acc.x += fq.x * w0.x + fq.y * w1.x + fq.z * w2.x + fq.w * w3.x;
        acc.y += fq.x * w0.y + fq.y * w1.y + fq.z * w2.y + fq.w * w3.y;
        acc.z += fq.x * w0.z + fq.y * w1.z + fq.z * w2.z + fq.w * w3.z;
        acc.w += fq.x * w0.w + fq.y * w1.w + fq.z * w2.w + fq.w * w3.w;
    }
    __syncthreads();
    for (int i = t * 4; i < 64 * 64; i += 1024)
        *(float4*)&Wh[i] = *(const float4*)&W2[64 * 64 + i];
    __syncthreads();
    #pragma unroll 2
    for (int k = 0; k < 64; k += 4) {
        float4 w0 = *(float4*)&Wh[(k + 0) * 64 + j02];
        float4 w1 = *(float4*)&Wh[(k + 1) * 64 + j02];
        float4 w2 = *(float4*)&Wh[(k + 2) * 64 + j02];
        float4 w3 = *(float4*)&Wh[(k + 3) * 64 + j02];
        float4 fq = *(float4*)&H[r2 * 128 + 64 + k];
        acc.x += fq.x * w0.x + fq.y * w1.x + fq.z * w2.x + fq.w * w3.x;
        acc.y += fq.x * w0.y + fq.y * w1.y + fq.z * w2.y + fq.w * w3.y;
        acc.z += fq.x * w0.z + fq.y * w1.z + fq.z * w2.z + fq.w * w3.z;
        acc.w += fq.x * w0.w + fq.y * w1.w + fq.z * w2.w + fq.w * w3.w;
    }
    const int r = row0 + r2;
    if (r < nrows) {
        float sc = rsqrtf((float)deg[r] + 1.0f);
        ushort4 v;
        v.x = f2bf(acc.x * sc); v.y = f2bf(acc.y * sc);
        v.z = f2bf(acc.z * sc); v.w = f2bf(acc.w * sc);
        *(ushort4*)&out[(long)r * 64 + j02] = v;
    }
}

// fused dense pair (MLP): fp32 dense input -> bf16 table out
template <bool S2_BIAS>
__global__ __launch_bounds__(256, 5) void fused2_k(
    const float* __restrict__ in, const float* __restrict__ W1,
    const float* __restrict__ b1, const float* __restrict__ W2,
    const float* __restrict__ b2, const int* __restrict__ deg,
    unsigned short* __restrict__ out, int nrows)
{
    __shared__ __align__(16) float Wh[32 * 128];
    __shared__ __align__(16) float F[16 * 64];
    __shared__ __align__(16) float H[16 * 128];
    const int t = threadIdx.x;
    const int row0 = blockIdx.x * 16;

    for (int i = t * 4; i < 16 * 64; i += 1024) {
        int r = i >> 6;
        float4 v = make_float4(0.f, 0.f, 0.f, 0.f);
        if (row0 + r < nrows) v = *(const float4*)&in[(long)row0 * 64 + i];
        *(float4*)&F[i] = v;
    }
    dense_pair_body<S2_BIAS>(Wh, F, H, W1, b1, W2, b2, deg, out, row0, nrows, t);
}

// ---------------------------------------------------------------------------
// fused GCN aggregation (bf16 gather) + dense pair -> bf16 table out
// ---------------------------------------------------------------------------
__global__ __launch_bounds__(256, 5) void gcnfused_k(
    const unsigned short* __restrict__ C, const int* __restrict__ deg,
    const int* __restrict__ edge_off,
    const float* __restrict__ W1, const float* __restrict__ b1,
    const float* __restrict__ W2, unsigned short* __restrict__ out,
    int nrows, int zoff)
{
    __shared__ __align__(16) float Wh[32 * 128];
    __shared__ __align__(16) float F[16 * 64];
    __shared__ __align__(16) float H[16 * 128];
    const int t = threadIdx.x;
    const int row0 = blockIdx.x * 16;
    const int wv = t >> 6, j = t & 63;
    const int col = (j & 15) << 3;

    const char* hb = (const char*)C;
    #pragma unroll
    for (int i = 0; i < 4; ++i) {
        const int r = wv * 4 + i;
        const int node = row0 + r;
        if (node < nrows) {
            float4 agg = csr_gather4_bf(hb, edge_off + ((long)node << CAPLOG),
                                        deg[node], j, zoff);
            float4 self = bf_row4(hb, (long)node << 7, col);
            float dv = rsqrtf((float)deg[node] + 1.0f);
            if ((j >> 4) == 0) {
                float4 res;
                res.x = dv * (self.x + agg.x);
                res.y = dv * (self.y + agg.y);
                res.z = dv * (self.z + agg.z);
                res.w = dv * (self.w + agg.w);
                *(float4*)&F[r * 64 + (j & 15) * 4] = res;
            }
        } else if ((j >> 4) == 0) {
            *(float4*)&F[r * 64 + (j & 15) * 4] = make_float4(0.f, 0.f, 0.f, 0.f);
        }
    }
    dense_pair_body<false>(Wh, F, H, W1, b1, W2, nullptr, deg, out, row0, nrows, t);
}

// ---------------------------------------------------------------------------
// fused final aggregation (bf16 gather) + output linear (fp32 out)
// ---------------------------------------------------------------------------
__global__ __launch_bounds__(256) void gatherout_k(
    const unsigned short* __restrict__ hp, const int* __restrict__ deg,
    const int* __restrict__ edge_off,
    const float* __restrict__ bg2, const float* __restrict__ Wl,
    const float* __restrict__ bl, float* __restrict__ out, int n, int zoff)
{
    __shared__ __align__(16) float WlL[64 * 64];
    __shared__ __align__(16) float vS[4][64];
    const int t = threadIdx.x;
    for (int i = t * 4; i < 64 * 64; i += 1024)
        *(float4*)&WlL[i] = *(const float4*)&Wl[i];
    __syncthreads();

    const int row0 = blockIdx.x * 16;
    const int wv = t >> 6, j = t & 63;
    const int col = (j & 15) << 3;
    const char* hb = (const char*)hp;
    const float blj = bl[j];
    const float4 bg4 = *(const float4*)&bg2[(j & 15) * 4];

    #pragma unroll
    for (int i = 0; i < 4; ++i) {
        const int node = row0 + wv * 4 + i;
        if (node >= n) continue;
        float4 agg = csr_gather4_bf(hb, edge_off + ((long)node << CAPLOG),
                                    deg[node], j, zoff);
        float4 self = bf_row4(hb, (long)node << 7, col);
        const float dv = rsqrtf((float)deg[node] + 1.0f);
        float4 vf;
        vf.x = fmaxf(dv * (self.x + agg.x) + bg4.x, 0.f);
        vf.y = fmaxf(dv * (self.y + agg.y) + bg4.y, 0.f);
        vf.z = fmaxf(dv * (self.z + agg.z) + bg4.z, 0.f);
        vf.w = fmaxf(dv * (self.w + agg.w) + bg4.w, 0.f);
        if ((j >> 4) == 0) *(float4*)&vS[wv][(j & 15) * 4] = vf;
        const float v = vS[wv][j];    // wave-internal LDS RAW, lgkmcnt ordered

        float o = blj;
        #pragma unroll 4
        for (int k = 0; k < 64; k += 4) {
            float vk0 = readlane_f(v, k + 0);
            float vk1 = readlane_f(v, k + 1);
            float vk2 = readlane_f(v, k + 2);
            float vk3 = readlane_f(v, k + 3);
            o += vk0 * WlL[(k + 0) * 64 + j] + vk1 * WlL[(k + 1) * 64 + j]
               + vk2 * WlL[(k + 2) * 64 + j] + vk3 * WlL[(k + 3) * 64 + j];
        }
        out[(long)node * 64 + j] = o;
    }
}

// ---------------------------------------------------------------------------
extern "C" void kernel_launch(void* const* d_in, const int* in_sizes, int n_in,
                              void* d_out, int out_size, void* d_ws, size_t ws_size,
                              hipStream_t stream) {
    const int*   src     = (const int*)  d_in[0];
    const int*   seg     = (const int*)  d_in[1];
    const int*   ei      = (const int*)  d_in[2];
    const float* src_emb = (const float*)d_in[3];
    const float* seg_emb = (const float*)d_in[4];
    const float* w       = (const float*)d_in[5];
    const float* Wq1     = (const float*)d_in[6];
    const float* bq1     = (const float*)d_in[7];
    const float* Wq2     = (const float*)d_in[8];
    const float* bq2     = (const float*)d_in[9];
    const float* Wg1     = (const float*)d_in[10];
    const float* bg1     = (const float*)d_in[11];
    const float* Wg2     = (const float*)d_in[12];
    const float* bg2     = (const float*)d_in[13];
    const float* Wl      = (const float*)d_in[14];
    const float* bl      = (const float*)d_in[15];
    float* out = (float*)d_out;

    const int N  = in_sizes[0] / 64;
    const int NE = in_sizes[2] / 2;
    const int VE = in_sizes[3];            // src_emb element count (V*64)
    const int* si = ei;
    const int* di = ei + NE;

    const size_t Npad  = ((size_t)N + 3) & ~(size_t)3;
    const size_t VEpad = ((size_t)VE + 7) & ~(size_t)7;
    int* cursor   = (int*)d_ws;                                   // deg after fill
    int* edge_off = cursor + Npad;                                // N*256 slots
    unsigned short* sbf = (unsigned short*)(edge_off + ((size_t)N << CAPLOG));
    float* A32 = (float*)(sbf + VEpad);                           // N*64 fp32
    unsigned short* Cbf = (unsigned short*)(A32 + (size_t)N * 64);   // N*64+64
    unsigned short* Abf = Cbf + (size_t)N * 64 + 64;                 // N*64+64
    const int zoff = N << 7;   // byte offset of bf16 sentinel zero row

    dim3 b256(256);
    const int convB = (VE + 1023) / 1024;
    const int zB    = (N + 255) / 256;
    const int eB    = (NE + 255) / 256;
    const int fB    = (N + 15) / 16;

    // dispatch 1: convert src_emb -> bf16, zero cursor, zero sentinels
    prep0_k<<<convB + zB, b256, 0, stream>>>(src_emb, sbf, VE, cursor, N,
                                             (unsigned*)(Cbf + (size_t)N * 64),
                                             (unsigned*)(Abf + (size_t)N * 64),
                                             convB);
    // dispatch 2: CSR fill (first eB blocks) co-launched with embedding
    prep1_k<<<eB + N, b256, 0, stream>>>(si, di, cursor, edge_off, NE, eB,
                                         src, seg, sbf, seg_emb, w, A32);

    // MLP pair fused: Cbf = bf16( rsqrt(deg+1) * (relu(A32@Wq1+bq1)@Wq2 + bq2) )
    fused2_k<true><<<fB, b256, 0, stream>>>(A32, Wq1, bq1, Wq2, bq2,
                                            cursor, Cbf, N);

    // GCN layer: bf16 gather(Cbf) -> dense pair -> Abf
    gcnfused_k<<<fB, b256, 0, stream>>>(Cbf, cursor, edge_off,
                                        Wg1, bg1, Wg2, Abf, N, zoff);

    // final bf16 gather(Abf) + bias/relu + output linear (fp32 out)
    gatherout_k<<<fB, b256, 0, stream>>>(Abf, cursor, edge_off, bg2,
                                         Wl, bl, out, N, zoff);
}